// Round 8
// baseline (182.498 us; speedup 1.0000x reference)
//
#include <hip/hip_runtime.h>

// GAGKNNQueryAndGroup: B=4, N=8192, NPOINT=2048, C=64, NSAMPLE=32, LAMBDA=0.5
// Output: (B, 3+C, NPOINT, NS) f32
//
// LAMBDA == 0.5 makes the component mask numerically irrelevant (d*0.5 both
// branches, order-preserving) -> components unused. Output is gathered data
// only, so monotone distance rescales leave results bit-identical.
//
// R8: SINGLE fused kernel. Each block computes exact top-32 for 8 queries
// (pass1 theta-bound -> pass2 candidate filter -> exact stable rank, identical
// math to the verified R6/R7 kernel), keeps the winner indices in LDS, then
// gathers xyz/features and writes the output tile directly. Removes: the
// transpose pass, featsT (8MB W + 8MB R), idxArr (1MB W+R), one dependent
// kernel launch, and the inter-kernel drain. features(B,C,N) is only 8MB ->
// L2/L3-resident, so the direct (strided) gather is latency-hidden by TLP.

#define BQ 4
#define NN_ 8192
#define NPOINT 2048
#define CF 64
#define NS 32
#define T1 256
#define PER (NN_ / T1)   // 32 points per thread
#define QB 8             // queries per block
#define CAPQ 128         // per-query candidate capacity (expected ~44)
#define M_EPS 1e-3f      // >> |fma-form - exact| rounding gap (~1e-5)

#define KNN_BLOCKS (BQ * NPOINT / QB)            // 1024

// LDS: region A (8192B): sMin[QB][T1] (pass1) / keys[QB][CAPQ] u64 (rank) --
// phases disjoint. region B (4096B): candI[QB][CAPQ] u32. Plus sTheta/cnt and
// the winner table sIdxLds[QB][NS] (1KB). Total ~13.4KB.
#define REG_A (QB * T1 * 4)
#define REG_B (QB * CAPQ * 4)
#define SMEM_BYTES (REG_A + REG_B)

__device__ __forceinline__ float rfl(float x) {
  return __int_as_float(__builtin_amdgcn_readfirstlane(__float_as_int(x)));
}

__global__ __launch_bounds__(256) void fused_kernel(
    const float* __restrict__ xyz, const float* __restrict__ new_xyz,
    const float* __restrict__ features, float* __restrict__ out) {
  __shared__ __align__(16) char smem[SMEM_BYTES];
  __shared__ float sTheta[QB];
  __shared__ int cnt[QB];
  __shared__ int sIdxLds[QB][NS];

  float(*sMin)[T1] = (float(*)[T1])smem;                                // region A
  unsigned long long(*keys)[CAPQ] = (unsigned long long(*)[CAPQ])smem;  // A, after pass1
  unsigned int(*candI)[CAPQ] = (unsigned int(*)[CAPQ])(smem + REG_A);   // region B

  const int tid = threadIdx.x;
  const int tile = blockIdx.x;
  const int b = tile / (NPOINT / QB);
  const int p0 = (tile % (NPOINT / QB)) * QB;   // local point base
  const int q0 = b * NPOINT + p0;               // global query base
  const int lane = tid & 63;
  const int wid = tid >> 6;

  // Block-uniform query constants -> SGPRs (readfirstlane).
  float qx2[QB], qy2[QB], qz2[QB], qnn[QB];
#pragma unroll
  for (int k = 0; k < QB; k++) {
    float ax = new_xyz[(q0 + k) * 3 + 0];
    float ay = new_xyz[(q0 + k) * 3 + 1];
    float az = new_xyz[(q0 + k) * 3 + 2];
    qx2[k] = rfl(-2.0f * ax);
    qy2[k] = rfl(-2.0f * ay);
    qz2[k] = rfl(-2.0f * az);
    qnn[k] = rfl(ax * ax + ay * ay + az * az);
  }

  const float4* __restrict__ base4 = (const float4*)(xyz + (size_t)b * NN_ * 3);

  float smin_r[QB];
#pragma unroll
  for (int k = 0; k < QB; k++) smin_r[k] = 3.4e38f;

  // ---- Pass 1 (rolled: I-cache resident; fma-form score t = pp - 2 p.q) ----
#pragma unroll 2
  for (int g = 0; g < PER / 4; g++) {          // 8 groups x 4 consecutive points
    const int v = g * 768 + tid * 3;           // float4 index of 48B group
    float4 v0 = base4[v + 0];                  // x0 y0 z0 x1
    float4 v1 = base4[v + 1];                  // y1 z1 x2 y2
    float4 v2 = base4[v + 2];                  // z2 x3 y3 z3
    float xs[4] = {v0.x, v0.w, v1.z, v2.y};
    float ys[4] = {v0.y, v1.x, v1.w, v2.z};
    float zs[4] = {v0.z, v1.y, v2.x, v2.w};
#pragma unroll
    for (int i = 0; i < 4; i++) {
      float pp = fmaf(zs[i], zs[i], fmaf(ys[i], ys[i], xs[i] * xs[i]));
#pragma unroll
      for (int k = 0; k < QB; k++) {
        float t = fmaf(xs[i], qx2[k], pp);
        t = fmaf(ys[i], qy2[k], t);
        t = fmaf(zs[i], qz2[k], t);
        smin_r[k] = fminf(smin_r[k], t);
      }
    }
  }

#pragma unroll
  for (int k = 0; k < QB; k++) sMin[k][tid] = smin_r[k];
  if (tid < QB) cnt[tid] = 0;
  __syncthreads();

  // ---- theta: wave w handles queries 2w,2w+1 (64-lane register bitonic).
  // theta_k = (32nd-smallest of 64 disjoint 128-point group minima) + |q|^2
  // + M_EPS: guaranteed upper bound on the true 32nd-smallest EXACT distance.
#pragma unroll
  for (int t2 = 0; t2 < 2; t2++) {
    const int k = wid * 2 + t2;
    float m = fminf(fminf(sMin[k][lane], sMin[k][lane + 64]),
                    fminf(sMin[k][lane + 128], sMin[k][lane + 192]));
#pragma unroll
    for (int kk = 2; kk <= 64; kk <<= 1) {
#pragma unroll
      for (int jj = kk >> 1; jj > 0; jj >>= 1) {
        float o = __shfl_xor(m, jj);
        bool up = ((lane & kk) == 0);
        bool lower = ((lane & jj) == 0);
        m = (up == lower) ? fminf(m, o) : fmaxf(m, o);
      }
    }
    if (lane == 31) sTheta[k] = m + qnn[k] + M_EPS;   // d-space upper bound
  }
  __syncthreads();

  float th2[QB];
#pragma unroll
  for (int k = 0; k < QB; k++)
    th2[k] = rfl(sTheta[k] + M_EPS - qnn[k]);   // prefilter bound (t-space)

  // ---- Pass 2 (rolled, tiny rare-path: push candidate index only) ----
#pragma unroll 1
  for (int g = 0; g < PER / 4; g++) {
    const int v = g * 768 + tid * 3;
    float4 v0 = base4[v + 0];
    float4 v1 = base4[v + 1];
    float4 v2 = base4[v + 2];
    float xs[4] = {v0.x, v0.w, v1.z, v2.y};
    float ys[4] = {v0.y, v1.x, v1.w, v2.z};
    float zs[4] = {v0.z, v1.y, v2.x, v2.w};
#pragma unroll
    for (int i = 0; i < 4; i++) {
      float pp = fmaf(zs[i], zs[i], fmaf(ys[i], ys[i], xs[i] * xs[i]));
      const int n = g * 1024 + tid * 4 + i;
#pragma unroll
      for (int k = 0; k < QB; k++) {
        float t = fmaf(xs[i], qx2[k], pp);
        t = fmaf(ys[i], qy2[k], t);
        t = fmaf(zs[i], qz2[k], t);
        if (t <= th2[k]) {
          int pos = atomicAdd(&cnt[k], 1);
          if (pos < CAPQ) candI[k][pos] = (unsigned)n;
        }
      }
    }
  }
  __syncthreads();

  // ---- Rank phase: exact distance + stable (d_bits, idx) rank per query.
  // Winners land in sIdxLds[k][0..31] (rank order == stable argsort order).
  const float* __restrict__ baseF = xyz + (size_t)b * NN_ * 3;
#pragma unroll
  for (int t2 = 0; t2 < 2; t2++) {
    const int k = wid * 2 + t2;
    const int qq = q0 + k;
    const int m = cnt[k] < CAPQ ? cnt[k] : CAPQ;
    // raw query coords (bit-exact reference values)
    const float qxk = new_xyz[qq * 3 + 0];
    const float qyk = new_xyz[qq * 3 + 1];
    const float qzk = new_xyz[qq * 3 + 2];

    unsigned long long keyreg[CAPQ / 64];
#pragma unroll
    for (int c = 0; c < CAPQ / 64; c++) {
      const int i = lane + c * 64;
      if (i < m) {
        const int n = (int)candI[k][i];
        float dx = baseF[n * 3 + 0] - qxk;
        float dy = baseF[n * 3 + 1] - qyk;
        float dz = baseF[n * 3 + 2] - qzk;
        // bit-exact reference distance: no FMA contraction, left-to-right sum
        float d = __fadd_rn(__fadd_rn(__fmul_rn(dx, dx), __fmul_rn(dy, dy)),
                            __fmul_rn(dz, dz));
        keyreg[c] = ((unsigned long long)__float_as_uint(d) << 32) | (unsigned)n;
      }
    }
    __syncthreads();   // candI fully read; region A (keys) safe to overwrite
#pragma unroll
    for (int c = 0; c < CAPQ / 64; c++) {
      const int i = lane + c * 64;
      if (i < m) keys[k][i] = keyreg[c];
    }
    __syncthreads();   // keys visible to all lanes
#pragma unroll
    for (int c = 0; c < CAPQ / 64; c++) {
      const int i = lane + c * 64;
      if (i < m) {
        unsigned long long x = keys[k][i];
        int r = 0;
        for (int j = 0; j < m; j++) r += (keys[k][j] < x) ? 1 : 0;
        if (r < NS) sIdxLds[k][r] = (int)(x & 0xffffffffu);
      }
    }
    __syncthreads();
  }
  // sIdxLds complete for all 8 queries (last loop iter ended with a barrier).

  // ---- Phase E: gather + write output directly ----
  // Feature rows (3..66): 8q x 64c x 8g = 4096 tuples -> 16 iterations.
  // Lanes g=0..7 of a group write one contiguous 128B row segment (dwordx4).
  // Source loads are strided gathers from L2/L3-resident features (8MB).
  const float* __restrict__ featB = features + (size_t)b * CF * NN_;
#pragma unroll 1
  for (int it = 0; it < 16; it++) {
    const int idx = it * 256 + tid;
    const int k = idx >> 9;           // query 0..7
    const int c = (idx >> 3) & 63;    // channel
    const int g = idx & 7;            // sample group (4 samples)
    const int n0 = sIdxLds[k][g * 4 + 0];
    const int n1 = sIdxLds[k][g * 4 + 1];
    const int n2 = sIdxLds[k][g * 4 + 2];
    const int n3 = sIdxLds[k][g * 4 + 3];
    const float* fr = featB + (size_t)c * NN_;
    float4 v = {fr[n0], fr[n1], fr[n2], fr[n3]};
    *(float4*)&out[(((size_t)b * 67 + (3 + c)) * NPOINT + (p0 + k)) * NS + g * 4] = v;
  }
  // xyz rows (0..2): 8q x 3r x 8g = 192 tuples (plain f32 subtract, exact).
  if (tid < 192) {
    const int k = tid / 24;
    const int rem = tid - k * 24;
    const int r = rem >> 3;
    const int g = rem & 7;
    const float qr = new_xyz[(q0 + k) * 3 + r];
    const int n0 = sIdxLds[k][g * 4 + 0];
    const int n1 = sIdxLds[k][g * 4 + 1];
    const int n2 = sIdxLds[k][g * 4 + 2];
    const int n3 = sIdxLds[k][g * 4 + 3];
    float4 v = {baseF[n0 * 3 + r] - qr, baseF[n1 * 3 + r] - qr,
                baseF[n2 * 3 + r] - qr, baseF[n3 * 3 + r] - qr};
    *(float4*)&out[(((size_t)b * 67 + r) * NPOINT + (p0 + k)) * NS + g * 4] = v;
  }
}

extern "C" void kernel_launch(void* const* d_in, const int* in_sizes, int n_in,
                              void* d_out, int out_size, void* d_ws, size_t ws_size,
                              hipStream_t stream) {
  const float* xyz      = (const float*)d_in[0];   // (4,8192,3)
  const float* new_xyz  = (const float*)d_in[1];   // (4,2048,3)
  // d_in[2], d_in[3]: components — unused (LAMBDA=0.5 makes mask a no-op)
  const float* features = (const float*)d_in[4];   // (4,64,8192)
  float* out = (float*)d_out;

  // Single fused dispatch; workspace unused.
  fused_kernel<<<KNN_BLOCKS, T1, 0, stream>>>(xyz, new_xyz, features, out);
}

// Round 9
// 129.553 us; speedup vs baseline: 1.4087x; 1.4087x over previous
//
#include <hip/hip_runtime.h>

// GAGKNNQueryAndGroup: B=4, N=8192, NPOINT=2048, C=64, NSAMPLE=32, LAMBDA=0.5
// Output: (B, 3+C, NPOINT, NS) f32
//
// LAMBDA == 0.5 makes the component mask numerically irrelevant (d*0.5 both
// branches, order-preserving) -> components unused. Output is gathered data
// only, so monotone distance rescales leave results bit-identical.
//
// R9 = exact revert to the verified best configuration (R6, 129.1 us):
//  - knn_tr_kernel: knn (rolled loops, I-cache resident, two-pass theta-bound
//    exact top-32) grid-fused with the features transpose.
//  - group_kernel: gather from featsT rows (coalesced 256B) via LDS, original
//    FSTR=68 layout, 8192 blocks.
// R7 (group rewrite) was +1.2us; R8 (full fusion, direct gather) was +53us
// from 16x cache-line over-fetch (FETCH 131MB vs 8MB input). featsT is the
// component that makes the gather coalesced -- it stays.

#define BQ 4
#define NN_ 8192
#define NPOINT 2048
#define CF 64
#define NS 32
#define T1 256
#define PER (NN_ / T1)   // 32 points per thread
#define QB 8             // queries per block (knn)
#define CAPQ 128         // per-query candidate capacity (expected ~44)
#define M_EPS 1e-3f      // >> |fma-form - exact| rounding gap (~1e-5)

#define KNN_BLOCKS (BQ * NPOINT / QB)            // 1024
#define TR_BLOCKS  ((NN_ / 32) * (CF / 32) * BQ) // 2048

// LDS arena (12,416B -> 8 blocks/CU, thread-capped, 100% wave ceiling):
//  region A (8192B): sMin[QB][T1] (pass1) / keys[QB][CAPQ] u64 (rank) /
//                    tr[32][33] (transpose path) -- phases disjoint.
//  region B (4096B): candI[QB][CAPQ] u32 (candidate indices)
//  region C (64B):   sTheta[QB] + cnt[QB]
#define REG_A (QB * T1 * 4)
#define REG_B (QB * CAPQ * 4)
#define SMEM_BYTES (REG_A + REG_B + QB * 4 + QB * 4)

__device__ __forceinline__ float rfl(float x) {
  return __int_as_float(__builtin_amdgcn_readfirstlane(__float_as_int(x)));
}

__global__ __launch_bounds__(256) void knn_tr_kernel(
    const float* __restrict__ xyz, const float* __restrict__ new_xyz,
    const float* __restrict__ features, int* __restrict__ idxOut,
    float* __restrict__ featsT) {
  __shared__ __align__(16) char smem[SMEM_BYTES];
  const int tid = threadIdx.x;

  if (blockIdx.x >= KNN_BLOCKS) {
    // ---------------- transpose path: features (B,C,N) -> (B,N,C) ----------
    float(*tr)[33] = (float(*)[33])smem;
    const int t = blockIdx.x - KNN_BLOCKS;
    const int n0 = (t & 255) * 32;
    const int c0 = ((t >> 8) & 1) * 32;
    const int b = t >> 9;
    const int tx = tid & 31;
    const int ty = tid >> 5;   // 0..7
#pragma unroll
    for (int i = 0; i < 4; i++) {
      int c = c0 + ty + i * 8;
      tr[ty + i * 8][tx] = features[(size_t)b * CF * NN_ + (size_t)c * NN_ + n0 + tx];
    }
    __syncthreads();
#pragma unroll
    for (int i = 0; i < 4; i++) {
      int nrow = n0 + ty + i * 8;
      featsT[(size_t)b * NN_ * CF + (size_t)nrow * CF + c0 + tx] = tr[tx][ty + i * 8];
    }
    return;
  }

  // ---------------- knn path: exact top-32, 8 queries/block ----------------
  // Pass 1 (rolled): fma-form score t = pp - 2 p.q (qx2 = -2 qx in SGPR).
  // theta_k = (32nd-smallest of 64 disjoint 128-point group minima) + |q|^2
  // + M_EPS: guaranteed upper bound on the true 32nd-smallest EXACT distance.
  // Pass 2 (rolled, tiny body): push candidate INDEX only for t <= th2.
  // Rank phase: recompute bit-exact reference distance for the ~44 candidates
  // per query, stable rank by (d_bits, idx). Extras with d>theta rank >=32 and
  // fall out naturally. Hot-loop code stays small -> I-cache resident.
  float(*sMin)[T1] = (float(*)[T1])smem;                         // region A
  unsigned long long(*keys)[CAPQ] = (unsigned long long(*)[CAPQ])smem;  // A, after pass1
  unsigned int(*candI)[CAPQ] = (unsigned int(*)[CAPQ])(smem + REG_A);   // region B
  float* sTheta = (float*)(smem + REG_A + REG_B);
  int* cnt = (int*)(smem + REG_A + REG_B + QB * 4);

  const int tile = blockIdx.x;
  const int b = tile / (NPOINT / QB);
  const int q0 = b * NPOINT + (tile % (NPOINT / QB)) * QB;
  const int lane = tid & 63;
  const int wid = tid >> 6;

  // Block-uniform query constants -> SGPRs (readfirstlane).
  float qx2[QB], qy2[QB], qz2[QB], qnn[QB];
#pragma unroll
  for (int k = 0; k < QB; k++) {
    float ax = new_xyz[(q0 + k) * 3 + 0];
    float ay = new_xyz[(q0 + k) * 3 + 1];
    float az = new_xyz[(q0 + k) * 3 + 2];
    qx2[k] = rfl(-2.0f * ax);
    qy2[k] = rfl(-2.0f * ay);
    qz2[k] = rfl(-2.0f * az);
    qnn[k] = rfl(ax * ax + ay * ay + az * az);
  }

  const float4* __restrict__ base4 = (const float4*)(xyz + (size_t)b * NN_ * 3);

  float smin_r[QB];
#pragma unroll
  for (int k = 0; k < QB; k++) smin_r[k] = 3.4e38f;

  // ---- Pass 1 (rolled: keep code small; I-cache was the R4/R5 bottleneck) ----
#pragma unroll 2
  for (int g = 0; g < PER / 4; g++) {          // 8 groups x 4 consecutive points
    const int v = g * 768 + tid * 3;           // float4 index of 48B group
    float4 v0 = base4[v + 0];                  // x0 y0 z0 x1
    float4 v1 = base4[v + 1];                  // y1 z1 x2 y2
    float4 v2 = base4[v + 2];                  // z2 x3 y3 z3
    float xs[4] = {v0.x, v0.w, v1.z, v2.y};
    float ys[4] = {v0.y, v1.x, v1.w, v2.z};
    float zs[4] = {v0.z, v1.y, v2.x, v2.w};
#pragma unroll
    for (int i = 0; i < 4; i++) {
      float pp = fmaf(zs[i], zs[i], fmaf(ys[i], ys[i], xs[i] * xs[i]));
#pragma unroll
      for (int k = 0; k < QB; k++) {
        float t = fmaf(xs[i], qx2[k], pp);
        t = fmaf(ys[i], qy2[k], t);
        t = fmaf(zs[i], qz2[k], t);
        smin_r[k] = fminf(smin_r[k], t);
      }
    }
  }

#pragma unroll
  for (int k = 0; k < QB; k++) sMin[k][tid] = smin_r[k];
  if (tid < QB) cnt[tid] = 0;
  __syncthreads();

  // ---- theta: wave w handles queries 2w,2w+1 (64-lane register bitonic) ----
#pragma unroll
  for (int t2 = 0; t2 < 2; t2++) {
    const int k = wid * 2 + t2;
    float m = fminf(fminf(sMin[k][lane], sMin[k][lane + 64]),
                    fminf(sMin[k][lane + 128], sMin[k][lane + 192]));
#pragma unroll
    for (int kk = 2; kk <= 64; kk <<= 1) {
#pragma unroll
      for (int jj = kk >> 1; jj > 0; jj >>= 1) {
        float o = __shfl_xor(m, jj);
        bool up = ((lane & kk) == 0);
        bool lower = ((lane & jj) == 0);
        m = (up == lower) ? fminf(m, o) : fmaxf(m, o);
      }
    }
    if (lane == 31) sTheta[k] = m + qnn[k] + M_EPS;   // d-space upper bound
  }
  __syncthreads();

  float th2[QB];
#pragma unroll
  for (int k = 0; k < QB; k++)
    th2[k] = rfl(sTheta[k] + M_EPS - qnn[k]);   // prefilter bound (t-space)

  // ---- Pass 2 (rolled, tiny rare-path: push index only) ----
#pragma unroll 1
  for (int g = 0; g < PER / 4; g++) {
    const int v = g * 768 + tid * 3;
    float4 v0 = base4[v + 0];
    float4 v1 = base4[v + 1];
    float4 v2 = base4[v + 2];
    float xs[4] = {v0.x, v0.w, v1.z, v2.y};
    float ys[4] = {v0.y, v1.x, v1.w, v2.z};
    float zs[4] = {v0.z, v1.y, v2.x, v2.w};
#pragma unroll
    for (int i = 0; i < 4; i++) {
      float pp = fmaf(zs[i], zs[i], fmaf(ys[i], ys[i], xs[i] * xs[i]));
      const int n = g * 1024 + tid * 4 + i;
#pragma unroll
      for (int k = 0; k < QB; k++) {
        float t = fmaf(xs[i], qx2[k], pp);
        t = fmaf(ys[i], qy2[k], t);
        t = fmaf(zs[i], qz2[k], t);
        if (t <= th2[k]) {
          int pos = atomicAdd(&cnt[k], 1);
          if (pos < CAPQ) candI[k][pos] = (unsigned)n;
        }
      }
    }
  }
  __syncthreads();

  // ---- Rank phase: exact distance + stable (d_bits, idx) rank per query ----
  const float* __restrict__ baseF = xyz + (size_t)b * NN_ * 3;
#pragma unroll
  for (int t2 = 0; t2 < 2; t2++) {
    const int k = wid * 2 + t2;
    const int qq = q0 + k;
    const int m = cnt[k] < CAPQ ? cnt[k] : CAPQ;
    // raw query coords (bit-exact reference values)
    const float qxk = new_xyz[qq * 3 + 0];
    const float qyk = new_xyz[qq * 3 + 1];
    const float qzk = new_xyz[qq * 3 + 2];

    unsigned long long keyreg[CAPQ / 64];
#pragma unroll
    for (int c = 0; c < CAPQ / 64; c++) {
      const int i = lane + c * 64;
      if (i < m) {
        const int n = (int)candI[k][i];
        float dx = baseF[n * 3 + 0] - qxk;
        float dy = baseF[n * 3 + 1] - qyk;
        float dz = baseF[n * 3 + 2] - qzk;
        // bit-exact reference distance: no FMA contraction, left-to-right sum
        float d = __fadd_rn(__fadd_rn(__fmul_rn(dx, dx), __fmul_rn(dy, dy)),
                            __fmul_rn(dz, dz));
        keyreg[c] = ((unsigned long long)__float_as_uint(d) << 32) | (unsigned)n;
      }
    }
    __syncthreads();   // candI fully read -> safe even if regions were reused
#pragma unroll
    for (int c = 0; c < CAPQ / 64; c++) {
      const int i = lane + c * 64;
      if (i < m) keys[k][i] = keyreg[c];
    }
    __syncthreads();   // keys visible to all lanes
#pragma unroll
    for (int c = 0; c < CAPQ / 64; c++) {
      const int i = lane + c * 64;
      if (i < m) {
        unsigned long long x = keys[k][i];
        int r = 0;
        for (int j = 0; j < m; j++) r += (keys[k][j] < x) ? 1 : 0;
        if (r < NS) idxOut[qq * NS + r] = (int)(x & 0xffffffffu);
      }
    }
    __syncthreads();
  }
}

// ---------------- Phase 2: gather + grouped write ----------------
#define FSTR 68   // LDS row stride: multiple of 4 (float4 stores), 4-way bank alias only
__global__ __launch_bounds__(256) void group_kernel(const float* __restrict__ xyz,
                                                    const float* __restrict__ new_xyz,
                                                    const float* __restrict__ featsT,
                                                    const int* __restrict__ idxArr,
                                                    float* __restrict__ out) {
  const int q = blockIdx.x;            // b*NPOINT + p
  const int b = q / NPOINT;
  const int p = q - b * NPOINT;
  const int tid = threadIdx.x;

  __shared__ int sIdx[NS];
  __shared__ __align__(16) float ldsF[NS * FSTR];
  __shared__ float ldsX[3 * NS];

  if (tid < NS) sIdx[tid] = idxArr[q * NS + tid];
  __syncthreads();

  {
    // 256 threads = 32 samples x 8 readers; each reader pulls 32B of the
    // 256B contiguous feature row for its sample.
    int s = tid >> 3, r = tid & 7;
    int nn = sIdx[s];
    const float4* src = (const float4*)(featsT + ((size_t)b * NN_ + nn) * CF);
    float4 v0 = src[r * 2];
    float4 v1 = src[r * 2 + 1];
    float4* dst = (float4*)(ldsF + s * FSTR + r * 8);
    dst[0] = v0;
    dst[1] = v1;
  }
  if (tid < 96) {
    int dd = tid >> 5, s = tid & 31;
    int nn = sIdx[s];
    ldsX[dd * NS + s] = xyz[((size_t)b * NN_ + nn) * 3 + dd] -
                        new_xyz[(size_t)q * 3 + dd];
  }
  __syncthreads();

  // Write 67 rows of 32 floats (128B coalesced per row), 8 rows at a time.
  const int s = tid & 31;
  const int r0 = tid >> 5;
#pragma unroll
  for (int k = 0; k < 9; k++) {
    int row = r0 + k * 8;
    if (row < 67) {
      float v = (row < 3) ? ldsX[row * NS + s] : ldsF[s * FSTR + (row - 3)];
      out[(((size_t)b * 67 + row) * NPOINT + p) * NS + s] = v;
    }
  }
}

extern "C" void kernel_launch(void* const* d_in, const int* in_sizes, int n_in,
                              void* d_out, int out_size, void* d_ws, size_t ws_size,
                              hipStream_t stream) {
  const float* xyz      = (const float*)d_in[0];   // (4,8192,3)
  const float* new_xyz  = (const float*)d_in[1];   // (4,2048,3)
  // d_in[2], d_in[3]: components — unused (LAMBDA=0.5 makes mask a no-op)
  const float* features = (const float*)d_in[4];   // (4,64,8192)
  float* out = (float*)d_out;

  // workspace layout: [idx: 4*2048*32 int = 1MB][featsT: 4*8192*64 f32 = 8MB]
  int* idxArr = (int*)d_ws;
  float* featsT = (float*)((char*)d_ws + (size_t)BQ * NPOINT * NS * sizeof(int));

  knn_tr_kernel<<<KNN_BLOCKS + TR_BLOCKS, T1, 0, stream>>>(xyz, new_xyz, features,
                                                           idxArr, featsT);
  group_kernel<<<BQ * NPOINT, T1, 0, stream>>>(xyz, new_xyz, featsT, idxArr, out);
}